// Round 16
// baseline (207.594 us; speedup 1.0000x reference)
//
#include <hip/hip_runtime.h>
#include <hip/hip_bf16.h>

typedef __bf16 bf16;
typedef __attribute__((ext_vector_type(4))) float f32x4;
typedef __attribute__((ext_vector_type(8))) __bf16 bf16x8;
typedef __attribute__((ext_vector_type(4))) __bf16 bf16x4;

// async global->LDS, 16B per lane; LDS dest must be wave-uniform base + lane*16
static __device__ __forceinline__ void gl16(const void* g, void* l) {
  __builtin_amdgcn_global_load_lds((const __attribute__((address_space(1))) void*)g,
                                   (__attribute__((address_space(3))) void*)l, 16, 0, 0);
}
// fragment read from a [*][64] bf16 tile, 16B-unit XOR swizzle by (row&7)
static __device__ __forceinline__ bf16x8 frag(const bf16* tile, int row, int kb) {
  return *(const bf16x8*)(tile + row * 64 + ((((kb) >> 3) ^ (row & 7)) << 3));
}

// ---------------------------------------------------------------------------
// Weight prepass: 4x [256][256] f32 -> bf16 row-major.
// ---------------------------------------------------------------------------
__global__ void wpre(const float* __restrict__ w0, const float* __restrict__ w1,
                     const float* __restrict__ w2, const float* __restrict__ w3,
                     bf16* __restrict__ dst) {
  const float* srcs[4] = {w0, w1, w2, w3};
  const float* s = srcs[blockIdx.y];
  bf16* d = dst + (size_t)blockIdx.y * 65536;
  int base = blockIdx.x * 2048 + threadIdx.x * 8;
  f32x4 a = *(const f32x4*)(s + base);
  f32x4 b = *(const f32x4*)(s + base + 4);
  bf16x8 v = {(bf16)a[0], (bf16)a[1], (bf16)a[2], (bf16)a[3],
              (bf16)b[0], (bf16)b[1], (bf16)b[2], (bf16)b[3]};
  *(bf16x8*)(d + base) = v;
}

// ---------------------------------------------------------------------------
// wq f32 [o][i] -> wqT bf16 [i][o]  (LDS tile transpose, tiny)
// ---------------------------------------------------------------------------
__global__ void wtr(const float* __restrict__ wq, bf16* __restrict__ wqT) {
  __shared__ float tl[64][65];
  const int r0 = blockIdx.x * 64, c0 = blockIdx.y * 64;
  const int t = threadIdx.x;
  const int cc = t & 63, rr = t >> 6;
#pragma unroll
  for (int i = 0; i < 16; ++i) {
    int r = i * 4 + rr;
    tl[r][cc] = wq[(size_t)(r0 + r) * 256 + c0 + cc];
  }
  __syncthreads();
#pragma unroll
  for (int i = 0; i < 16; ++i) {
    int r = i * 4 + rr;
    wqT[(size_t)(c0 + r) * 256 + r0 + cc] = (bf16)tl[cc][r];
  }
}

// ===========================================================================
// K+V projection (unchanged from round 15, single-stage).
// ===========================================================================
__global__ __launch_bounds__(256, 1)
void kv_proj(const float* __restrict__ key,
             const bf16* __restrict__ Wk, const float* __restrict__ bk, bf16* __restrict__ Kpm,
             const bf16* __restrict__ Wv, const float* __restrict__ bv, bf16* __restrict__ Vpm) {
  __shared__ alignas(16) char smem[64 * 264 * 2];
  const int P = 1600;
  const int t = threadIdx.x;
  const int b = blockIdx.z;
  const int p0 = blockIdx.x * 64;
  const int sel = blockIdx.y;
  const bf16* W = sel ? Wv : Wk;
  const float* bias = sel ? bv : bk;
  bf16* out = sel ? Vpm : Kpm;
  const int w = t >> 6, l = t & 63;
  const int lrow = l & 15, ksel = l >> 4;
  const int pq = t & 15, cq = t >> 4;
  const float* actb = key + (size_t)b * 256 * P;
  bf16* As = (bf16*)smem;

  f32x4 Ar[4][4];
#pragma unroll
  for (int kt = 0; kt < 4; ++kt)
#pragma unroll
    for (int j = 0; j < 4; ++j)
      Ar[kt][j] = *(const f32x4*)(actb + (size_t)(kt * 64 + cq * 4 + j) * P + p0 + pq * 4);
#pragma unroll
  for (int kt = 0; kt < 4; ++kt) {
    bf16* tile = As + kt * 4096;
#pragma unroll
    for (int e = 0; e < 4; ++e) {
      int row = pq * 4 + e;
      bf16x4 v = {(bf16)Ar[kt][0][e], (bf16)Ar[kt][1][e], (bf16)Ar[kt][2][e], (bf16)Ar[kt][3][e]};
      *(bf16x4*)(tile + row * 64 + ((((cq >> 1) ^ (row & 7)) << 3) | ((cq & 1) << 2))) = v;
    }
  }
  __syncthreads();

  f32x4 acc[4][4];
#pragma unroll
  for (int i = 0; i < 4; ++i)
#pragma unroll
    for (int j = 0; j < 4; ++j) acc[i][j] = (f32x4){0.f, 0.f, 0.f, 0.f};

#pragma unroll
  for (int kt = 0; kt < 4; ++kt) {
    const int k0 = kt * 64;
    const bf16* tile = As + kt * 4096;
    bf16x8 af[4][2], bv8[4][2];
#pragma unroll
    for (int mi = 0; mi < 4; ++mi)
#pragma unroll
      for (int kk = 0; kk < 2; ++kk)
        af[mi][kk] = *(const bf16x8*)(W + (size_t)(w * 64 + mi * 16 + lrow) * 256 +
                                      k0 + kk * 32 + ksel * 8);
#pragma unroll
    for (int ni = 0; ni < 4; ++ni)
#pragma unroll
      for (int kk = 0; kk < 2; ++kk)
        bv8[ni][kk] = frag(tile, ni * 16 + lrow, kk * 32 + ksel * 8);
#pragma unroll
    for (int kk = 0; kk < 2; ++kk)
#pragma unroll
      for (int mi = 0; mi < 4; ++mi)
#pragma unroll
        for (int ni = 0; ni < 4; ++ni)
          acc[mi][ni] = __builtin_amdgcn_mfma_f32_16x16x32_bf16(af[mi][kk], bv8[ni][kk],
                                                                acc[mi][ni], 0, 0, 0);
  }
  __syncthreads();

  bf16* Sc = (bf16*)smem;
#pragma unroll
  for (int mi = 0; mi < 4; ++mi) {
#pragma unroll
    for (int r = 0; r < 4; ++r) {
      int o = w * 64 + mi * 16 + ksel * 4 + r;
      float bvf = bias[o];
#pragma unroll
      for (int ni = 0; ni < 4; ++ni) {
        int px = ni * 16 + lrow;
        Sc[px * 264 + o] = (bf16)(acc[mi][ni][r] + bvf);
      }
    }
  }
  __syncthreads();
  bf16* ob = out + (size_t)b * P * 256 + (size_t)p0 * 256;
#pragma unroll
  for (int pass = 0; pass < 8; ++pass) {
    int idx = pass * 256 + t;
    int row = idx >> 5, cu = idx & 31;
    bf16x8 v = *(const bf16x8*)(Sc + row * 264 + cu * 8);
    *(bf16x8*)(ob + (size_t)row * 256 + cu * 8) = v;
  }
}

// ===========================================================================
// uv_gemm: D[b*4+hd][o][q] = sum_{c<64} A[o][hd*64+c] * Bpm[b*1600+q][hd*64+c]
// Used twice: (Kpm, wqT) -> T   and   (Vpm, wo) -> Uv.   (unchanged structure)
// ===========================================================================
__global__ __launch_bounds__(256, 4)
void uv_gemm(const bf16* __restrict__ Bpm, const bf16* __restrict__ A,
             bf16* __restrict__ D) {
  __shared__ alignas(16) bf16 Vt[64 * 64];
  const int t = threadIdx.x;
  const int b = blockIdx.z;
  const int hd = blockIdx.y;
  const int q0 = blockIdx.x * 64;
  const int w = t >> 6, l = t & 63;
  const int lrow = l & 15, ksel = l >> 4;

  const bf16* vsrc = Bpm + ((size_t)b * 1600 + q0) * 256 + hd * 64;
#pragma unroll
  for (int call = 0; call < 2; ++call) {
    int idx = (w * 2 + call) * 64 + l;
    int q = idx >> 3, u = idx & 7;
    gl16(vsrc + (size_t)q * 256 + ((u ^ (q & 7)) << 3), Vt + idx * 8);
  }
  asm volatile("s_waitcnt vmcnt(0)" ::: "memory");
  __syncthreads();

  f32x4 acc[4][4];
#pragma unroll
  for (int i = 0; i < 4; ++i)
#pragma unroll
    for (int j = 0; j < 4; ++j) acc[i][j] = (f32x4){0.f, 0.f, 0.f, 0.f};

#pragma unroll
  for (int kk = 0; kk < 2; ++kk) {
    bf16x8 af[4], bv[4];
#pragma unroll
    for (int mi = 0; mi < 4; ++mi)
      af[mi] = *(const bf16x8*)(A + (size_t)(w * 64 + mi * 16 + lrow) * 256 +
                                hd * 64 + kk * 32 + ksel * 8);
#pragma unroll
    for (int ni = 0; ni < 4; ++ni)
      bv[ni] = frag(Vt, ni * 16 + lrow, kk * 32 + ksel * 8);
#pragma unroll
    for (int mi = 0; mi < 4; ++mi)
#pragma unroll
      for (int ni = 0; ni < 4; ++ni)
        acc[mi][ni] = __builtin_amdgcn_mfma_f32_16x16x32_bf16(af[mi], bv[ni], acc[mi][ni], 0, 0, 0);
  }

  bf16* ob = D + ((size_t)(b * 4 + hd)) * 256 * 1600;
#pragma unroll
  for (int mi = 0; mi < 4; ++mi) {
#pragma unroll
    for (int ni = 0; ni < 4; ++ni) {
#pragma unroll
      for (int r = 0; r < 4; ++r) {
        int o = w * 64 + mi * 16 + ksel * 4 + r;
        int q = q0 + ni * 16 + lrow;
        ob[(size_t)o * 1600 + q] = (bf16)acc[mi][ni][r];
      }
    }
  }
}

// ---------------------------------------------------------------------------
// beta[b][hd][q] = sum_{c<64} bq[hd*64+c] * Kpm[b*1600+q][hd*64+c]   (bf16)
// ---------------------------------------------------------------------------
__global__ void beta_k(const bf16* __restrict__ Kpm, const float* __restrict__ bq,
                       bf16* __restrict__ beta) {
  __shared__ float bqs[256];
  const int t = threadIdx.x;
  bqs[t] = bq[t];
  __syncthreads();
  const int b = blockIdx.y;
  const int q = blockIdx.x * 64 + (t >> 2);
  const int hd = t & 3;
  const bf16* row = Kpm + ((size_t)b * 1600 + q) * 256 + hd * 64;
  float s = 0.f;
#pragma unroll
  for (int i = 0; i < 8; ++i) {
    bf16x8 v = *(const bf16x8*)(row + i * 8);
#pragma unroll
    for (int j = 0; j < 8; ++j) s += (float)v[j] * bqs[hd * 64 + i * 8 + j];
  }
  beta[((size_t)b * 4 + hd) * 1600 + q] = (bf16)s;
}

// ===========================================================================
// stream_score: score[b][hd][p] = 0.0625*( sum_i query[i,p]*bilerp(T[hd][i])(p)
//                                          + bilerp(beta[hd])(p) )
// Block = 256 consecutive pixels x 1 batch. Thread owns ONE pixel (interp
// indices/weights in registers). T staged in 16 chunks of (4hd x 16i) rows x
// 192-q window via gl16 (dbuf). query reads are CONTIGUOUS 1KB/row/wave.
// ===========================================================================
__global__ __launch_bounds__(256, 3)
void stream_score(const float* __restrict__ query, const bf16* __restrict__ T,
                  const bf16* __restrict__ beta, float* __restrict__ score) {
  __shared__ alignas(16) bf16 Tc[2][64][192];  // 49.2KB dbuf
  __shared__ bf16 Bs[4][192];
  const int t = threadIdx.x;
  const int p0 = blockIdx.x * 256;
  const int b = blockIdx.y;
  const int px = p0 + t;
  const int x = px / 80, y = px % 80;

  // block-uniform q-window base (row span <= 4 x-rows => 160 < 192)
  const int x_min = p0 / 80;
  int ixm = (int)floorf(0.5f * x_min - 0.25f);
  int xr0 = ixm < 0 ? 0 : ixm;
  int qbase = xr0 * 40;
  if (qbase > 1408) qbase = 1408;

  // per-thread interp (registers)
  float cx = 0.5f * x - 0.25f;
  int ix = (int)floorf(cx);
  float wx1 = cx - ix;
  int x0 = ix < 0 ? 0 : ix, x1 = (ix + 1 > 39) ? 39 : ix + 1;
  float cy = 0.5f * y - 0.25f;
  int iy = (int)floorf(cy);
  float wy1 = cy - iy;
  int y0 = iy < 0 ? 0 : iy, y1 = (iy + 1 > 39) ? 39 : iy + 1;
  const float w00 = (1.f - wx1) * (1.f - wy1), w01 = (1.f - wx1) * wy1;
  const float w10 = wx1 * (1.f - wy1), w11 = wx1 * wy1;
  const int r00 = x0 * 40 + y0 - qbase, r01 = x0 * 40 + y1 - qbase;
  const int r10 = x1 * 40 + y0 - qbase, r11 = x1 * 40 + y1 - qbase;

  // stage beta window
  for (int i = t; i < 768; i += 256) {
    int hd = i / 192, qq = i - hd * 192;
    Bs[hd][qq] = beta[((size_t)b * 4 + hd) * 1600 + qbase + qq];
  }

  const bf16* Tb = T + (size_t)b * 4 * 256 * 1600;

  auto STAGE = [&](int c, int buf) {
    const int k0 = c * 16;
#pragma unroll
    for (int call = 0; call < 6; ++call) {
      int idx = call * 256 + t;        // 1536 units: row r = idx/24, u = idx%24
      int r = idx / 24, u = idx - r * 24;
      int hd = r >> 4, kk = r & 15;
      const bf16* src = Tb + ((size_t)(hd * 256) + k0 + kk) * 1600 + qbase + u * 8;
      gl16(src, &Tc[buf][0][0] + idx * 8);
    }
  };

  STAGE(0, 0);
  asm volatile("s_waitcnt vmcnt(0)" ::: "memory");
  __syncthreads();

  float acc[4];
#pragma unroll
  for (int hd = 0; hd < 4; ++hd)
    acc[hd] = w00 * (float)Bs[hd][r00] + w01 * (float)Bs[hd][r01] +
              w10 * (float)Bs[hd][r10] + w11 * (float)Bs[hd][r11];

  int buf = 0;
  for (int c = 0; c < 16; ++c) {
    if (c < 15) STAGE(c + 1, buf ^ 1);
    float qv[16];
#pragma unroll
    for (int kk = 0; kk < 16; ++kk)
      qv[kk] = query[((size_t)b * 256 + c * 16 + kk) * 6400 + px];
#pragma unroll
    for (int kk = 0; kk < 16; ++kk) {
#pragma unroll
      for (int hd = 0; hd < 4; ++hd) {
        const bf16* row = &Tc[buf][hd * 16 + kk][0];
        float tv = w00 * (float)row[r00] + w01 * (float)row[r01] +
                   w10 * (float)row[r10] + w11 * (float)row[r11];
        acc[hd] += qv[kk] * tv;
      }
    }
    asm volatile("s_waitcnt vmcnt(0)" ::: "memory");
    __syncthreads();
    buf ^= 1;
  }

#pragma unroll
  for (int hd = 0; hd < 4; ++hd)
    score[((size_t)b * 4 + hd) * 6400 + px] = 0.0625f * acc[hd];
}

// ---------------------------------------------------------------------------
// In-place column softmax over x (per b,hd,y), x4 (R2 sum) folded in.
// ---------------------------------------------------------------------------
__global__ void smax_kernel(float* __restrict__ score) {
  __shared__ float s[6400];
  const int hd = blockIdx.x, b = blockIdx.y, t = threadIdx.x;
  float* buf = score + ((size_t)b * 4 + hd) * 6400;
  for (int i = t; i < 6400; i += 256) s[i] = buf[i];
  __syncthreads();
  if (t < 80) {
    const int y = t;
    float m = -1e30f;
    for (int x = 0; x < 80; ++x) m = fmaxf(m, s[x * 80 + y]);
    float sum = 0.f;
    for (int x = 0; x < 80; ++x) {
      float e = __expf(s[x * 80 + y] - m);
      s[x * 80 + y] = e;
      sum += e;
    }
    float inv = 4.0f / sum;
    for (int x = 0; x < 80; ++x) buf[x * 80 + y] = s[x * 80 + y] * inv;
  }
}

// ===========================================================================
// combine (unchanged): one block per (o, b), coalesced writes.
// ===========================================================================
__global__ __launch_bounds__(256, 8)
void combine(const bf16* __restrict__ Uv, const float* __restrict__ attn,
             const float* __restrict__ bo, float* __restrict__ out) {
  __shared__ bf16 Us[4][1600];
  __shared__ int   sx0[80], sx1[80];
  __shared__ float swx[80];
  const int t = threadIdx.x;
  const int o = blockIdx.x;
  const int b = blockIdx.y;

  const bf16* usrc = Uv + (size_t)(b * 4) * 256 * 1600 + (size_t)o * 1600;
  for (int idx = t; idx < 800; idx += 256) {
    int hd = idx / 200, u = idx % 200;
    *(bf16x8*)&Us[hd][u * 8] = *(const bf16x8*)(usrc + (size_t)hd * 256 * 1600 + u * 8);
  }
  if (t < 80) {
    float c = 0.5f * t - 0.25f;
    int i0 = (int)floorf(c);
    swx[t] = c - i0;
    sx0[t] = i0 < 0 ? 0 : i0;
    sx1[t] = (i0 + 1 > 39) ? 39 : i0 + 1;
  }
  __syncthreads();

  const float bias = bo[o];
  const float* attb = attn + (size_t)b * 4 * 6400;
  float* op = out + ((size_t)b * 256 + o) * 6400;

  for (int p = t; p < 6400; p += 256) {
    int x = p / 80, y = p - x * 80;
    int x0 = sx0[x], x1 = sx1[x], y0 = sx0[y], y1 = sx1[y];
    float wx1 = swx[x], wy1 = swx[y];
    float w00 = (1.f - wx1) * (1.f - wy1), w01 = (1.f - wx1) * wy1;
    float w10 = wx1 * (1.f - wy1), w11 = wx1 * wy1;
    int q00 = x0 * 40 + y0, q01 = x0 * 40 + y1, q10 = x1 * 40 + y0, q11 = x1 * 40 + y1;
    float acc = bias;
#pragma unroll
    for (int hd = 0; hd < 4; ++hd) {
      float up = w00 * (float)Us[hd][q00] + w01 * (float)Us[hd][q01] +
                 w10 * (float)Us[hd][q10] + w11 * (float)Us[hd][q11];
      acc += attb[hd * 6400 + p] * up;
    }
    op[p] = acc;
  }
}

// ---------------------------------------------------------------------------
extern "C" void kernel_launch(void* const* d_in, const int* in_sizes, int n_in,
                              void* d_out, int out_size, void* d_ws, size_t ws_size,
                              hipStream_t stream) {
  const float* query = (const float*)d_in[0];
  const float* key   = (const float*)d_in[1];
  const float* wq    = (const float*)d_in[2];
  const float* bq    = (const float*)d_in[3];
  const float* wk    = (const float*)d_in[4];
  const float* bk    = (const float*)d_in[5];
  const float* wv    = (const float*)d_in[6];
  const float* bv    = (const float*)d_in[7];
  const float* wo    = (const float*)d_in[8];
  const float* bo    = (const float*)d_in[9];

  // ws (85.7MB): [T | later Uv] | Kpm | Vpm | score | Wb.
  // wqT + beta live in d_out scratch (dead before combine writes d_out).
  char* ws = (char*)d_ws;
  bf16*  T     = (bf16*)(ws);              // 52,428,800 B (dead after stream_score)
  bf16*  Uv    = (bf16*)(ws);              // written by uv_gemm (after smax)
  bf16*  Kpm   = (bf16*)(ws + 52428800);   // 13,107,200 B
  bf16*  Vpm   = (bf16*)(ws + 65536000);   // 13,107,200 B
  float* score = (float*)(ws + 78643200);  //  6,553,600 B
  bf16*  Wb    = (bf16*)(ws + 85196800);   //    524,288 B
  bf16* wqb = Wb, *wkb = Wb + 65536, *wvb = Wb + 131072, *wob = Wb + 196608;
  (void)wqb;
  bf16*  wqT   = (bf16*)d_out;                     // 131,072 B scratch
  bf16*  beta  = (bf16*)((char*)d_out + 131072);   // 204,800 B scratch

  wpre<<<dim3(32, 4), 256, 0, stream>>>(wq, wk, wv, wo, Wb);
  wtr<<<dim3(4, 4), 256, 0, stream>>>(wq, wqT);
  kv_proj<<<dim3(25, 2, 16), 256, 0, stream>>>(key, wkb, bk, Kpm, wvb, bv, Vpm);
  uv_gemm<<<dim3(25, 4, 16), 256, 0, stream>>>(Kpm, wqT, T);    // T-gemm
  beta_k<<<dim3(25, 16), 256, 0, stream>>>(Kpm, bq, beta);
  stream_score<<<dim3(25, 16), 256, 0, stream>>>(query, T, beta, score);
  smax_kernel<<<dim3(4, 16), 256, 0, stream>>>(score);
  uv_gemm<<<dim3(25, 4, 16), 256, 0, stream>>>(Vpm, wob, Uv);
  combine<<<dim3(256, 16), 256, 0, stream>>>(Uv, score, bo, (float*)d_out);
}

// Round 17
// 191.562 us; speedup vs baseline: 1.0837x; 1.0837x over previous
//
#include <hip/hip_runtime.h>
#include <hip/hip_bf16.h>

typedef __bf16 bf16;
typedef __attribute__((ext_vector_type(4))) float f32x4;
typedef __attribute__((ext_vector_type(8))) __bf16 bf16x8;
typedef __attribute__((ext_vector_type(4))) __bf16 bf16x4;

// async global->LDS, 16B per lane; LDS dest must be wave-uniform base + lane*16
static __device__ __forceinline__ void gl16(const void* g, void* l) {
  __builtin_amdgcn_global_load_lds((const __attribute__((address_space(1))) void*)g,
                                   (__attribute__((address_space(3))) void*)l, 16, 0, 0);
}
// fragment read from a [*][64] bf16 tile, 16B-unit XOR swizzle by (row&7)
static __device__ __forceinline__ bf16x8 frag(const bf16* tile, int row, int kb) {
  return *(const bf16x8*)(tile + row * 64 + ((((kb) >> 3) ^ (row & 7)) << 3));
}

// ---------------------------------------------------------------------------
// Weight prepass: 4x [256][256] f32 -> bf16 row-major.
// ---------------------------------------------------------------------------
__global__ void wpre(const float* __restrict__ w0, const float* __restrict__ w1,
                     const float* __restrict__ w2, const float* __restrict__ w3,
                     bf16* __restrict__ dst) {
  const float* srcs[4] = {w0, w1, w2, w3};
  const float* s = srcs[blockIdx.y];
  bf16* d = dst + (size_t)blockIdx.y * 65536;
  int base = blockIdx.x * 2048 + threadIdx.x * 8;
  f32x4 a = *(const f32x4*)(s + base);
  f32x4 b = *(const f32x4*)(s + base + 4);
  bf16x8 v = {(bf16)a[0], (bf16)a[1], (bf16)a[2], (bf16)a[3],
              (bf16)b[0], (bf16)b[1], (bf16)b[2], (bf16)b[3]};
  *(bf16x8*)(d + base) = v;
}

// ---------------------------------------------------------------------------
// wq f32 [o][i] -> wqT bf16 [i][o]  (LDS tile transpose, tiny)
// ---------------------------------------------------------------------------
__global__ void wtr(const float* __restrict__ wq, bf16* __restrict__ wqT) {
  __shared__ float tl[64][65];
  const int r0 = blockIdx.x * 64, c0 = blockIdx.y * 64;
  const int t = threadIdx.x;
  const int cc = t & 63, rr = t >> 6;
#pragma unroll
  for (int i = 0; i < 16; ++i) {
    int r = i * 4 + rr;
    tl[r][cc] = wq[(size_t)(r0 + r) * 256 + c0 + cc];
  }
  __syncthreads();
#pragma unroll
  for (int i = 0; i < 16; ++i) {
    int r = i * 4 + rr;
    wqT[(size_t)(c0 + r) * 256 + r0 + cc] = (bf16)tl[cc][r];
  }
}

// ===========================================================================
// K+V projection (unchanged).
// ===========================================================================
__global__ __launch_bounds__(256, 1)
void kv_proj(const float* __restrict__ key,
             const bf16* __restrict__ Wk, const float* __restrict__ bk, bf16* __restrict__ Kpm,
             const bf16* __restrict__ Wv, const float* __restrict__ bv, bf16* __restrict__ Vpm) {
  __shared__ alignas(16) char smem[64 * 264 * 2];
  const int P = 1600;
  const int t = threadIdx.x;
  const int b = blockIdx.z;
  const int p0 = blockIdx.x * 64;
  const int sel = blockIdx.y;
  const bf16* W = sel ? Wv : Wk;
  const float* bias = sel ? bv : bk;
  bf16* out = sel ? Vpm : Kpm;
  const int w = t >> 6, l = t & 63;
  const int lrow = l & 15, ksel = l >> 4;
  const int pq = t & 15, cq = t >> 4;
  const float* actb = key + (size_t)b * 256 * P;
  bf16* As = (bf16*)smem;

  f32x4 Ar[4][4];
#pragma unroll
  for (int kt = 0; kt < 4; ++kt)
#pragma unroll
    for (int j = 0; j < 4; ++j)
      Ar[kt][j] = *(const f32x4*)(actb + (size_t)(kt * 64 + cq * 4 + j) * P + p0 + pq * 4);
#pragma unroll
  for (int kt = 0; kt < 4; ++kt) {
    bf16* tile = As + kt * 4096;
#pragma unroll
    for (int e = 0; e < 4; ++e) {
      int row = pq * 4 + e;
      bf16x4 v = {(bf16)Ar[kt][0][e], (bf16)Ar[kt][1][e], (bf16)Ar[kt][2][e], (bf16)Ar[kt][3][e]};
      *(bf16x4*)(tile + row * 64 + ((((cq >> 1) ^ (row & 7)) << 3) | ((cq & 1) << 2))) = v;
    }
  }
  __syncthreads();

  f32x4 acc[4][4];
#pragma unroll
  for (int i = 0; i < 4; ++i)
#pragma unroll
    for (int j = 0; j < 4; ++j) acc[i][j] = (f32x4){0.f, 0.f, 0.f, 0.f};

#pragma unroll
  for (int kt = 0; kt < 4; ++kt) {
    const int k0 = kt * 64;
    const bf16* tile = As + kt * 4096;
    bf16x8 af[4][2], bv8[4][2];
#pragma unroll
    for (int mi = 0; mi < 4; ++mi)
#pragma unroll
      for (int kk = 0; kk < 2; ++kk)
        af[mi][kk] = *(const bf16x8*)(W + (size_t)(w * 64 + mi * 16 + lrow) * 256 +
                                      k0 + kk * 32 + ksel * 8);
#pragma unroll
    for (int ni = 0; ni < 4; ++ni)
#pragma unroll
      for (int kk = 0; kk < 2; ++kk)
        bv8[ni][kk] = frag(tile, ni * 16 + lrow, kk * 32 + ksel * 8);
#pragma unroll
    for (int kk = 0; kk < 2; ++kk)
#pragma unroll
      for (int mi = 0; mi < 4; ++mi)
#pragma unroll
        for (int ni = 0; ni < 4; ++ni)
          acc[mi][ni] = __builtin_amdgcn_mfma_f32_16x16x32_bf16(af[mi][kk], bv8[ni][kk],
                                                                acc[mi][ni], 0, 0, 0);
  }
  __syncthreads();

  bf16* Sc = (bf16*)smem;
#pragma unroll
  for (int mi = 0; mi < 4; ++mi) {
#pragma unroll
    for (int r = 0; r < 4; ++r) {
      int o = w * 64 + mi * 16 + ksel * 4 + r;
      float bvf = bias[o];
#pragma unroll
      for (int ni = 0; ni < 4; ++ni) {
        int px = ni * 16 + lrow;
        Sc[px * 264 + o] = (bf16)(acc[mi][ni][r] + bvf);
      }
    }
  }
  __syncthreads();
  bf16* ob = out + (size_t)b * P * 256 + (size_t)p0 * 256;
#pragma unroll
  for (int pass = 0; pass < 8; ++pass) {
    int idx = pass * 256 + t;
    int row = idx >> 5, cu = idx & 31;
    bf16x8 v = *(const bf16x8*)(Sc + row * 264 + cu * 8);
    *(bf16x8*)(ob + (size_t)row * 256 + cu * 8) = v;
  }
}

// ===========================================================================
// uv_gemm: D[b*4+hd][o][q] = sum_{c<64} A[o][hd*64+c] * Bpm[b*1600+q][hd*64+c]
// Used twice: (Kpm, wqT) -> T   and   (Vpm, wo) -> Uv.
// ===========================================================================
__global__ __launch_bounds__(256, 4)
void uv_gemm(const bf16* __restrict__ Bpm, const bf16* __restrict__ A,
             bf16* __restrict__ D) {
  __shared__ alignas(16) bf16 Vt[64 * 64];
  const int t = threadIdx.x;
  const int b = blockIdx.z;
  const int hd = blockIdx.y;
  const int q0 = blockIdx.x * 64;
  const int w = t >> 6, l = t & 63;
  const int lrow = l & 15, ksel = l >> 4;

  const bf16* vsrc = Bpm + ((size_t)b * 1600 + q0) * 256 + hd * 64;
#pragma unroll
  for (int call = 0; call < 2; ++call) {
    int idx = (w * 2 + call) * 64 + l;
    int q = idx >> 3, u = idx & 7;
    gl16(vsrc + (size_t)q * 256 + ((u ^ (q & 7)) << 3), Vt + idx * 8);
  }
  asm volatile("s_waitcnt vmcnt(0)" ::: "memory");
  __syncthreads();

  f32x4 acc[4][4];
#pragma unroll
  for (int i = 0; i < 4; ++i)
#pragma unroll
    for (int j = 0; j < 4; ++j) acc[i][j] = (f32x4){0.f, 0.f, 0.f, 0.f};

#pragma unroll
  for (int kk = 0; kk < 2; ++kk) {
    bf16x8 af[4], bv[4];
#pragma unroll
    for (int mi = 0; mi < 4; ++mi)
      af[mi] = *(const bf16x8*)(A + (size_t)(w * 64 + mi * 16 + lrow) * 256 +
                                hd * 64 + kk * 32 + ksel * 8);
#pragma unroll
    for (int ni = 0; ni < 4; ++ni)
      bv[ni] = frag(Vt, ni * 16 + lrow, kk * 32 + ksel * 8);
#pragma unroll
    for (int mi = 0; mi < 4; ++mi)
#pragma unroll
      for (int ni = 0; ni < 4; ++ni)
        acc[mi][ni] = __builtin_amdgcn_mfma_f32_16x16x32_bf16(af[mi], bv[ni], acc[mi][ni], 0, 0, 0);
  }

  bf16* ob = D + ((size_t)(b * 4 + hd)) * 256 * 1600;
#pragma unroll
  for (int mi = 0; mi < 4; ++mi) {
#pragma unroll
    for (int ni = 0; ni < 4; ++ni) {
#pragma unroll
      for (int r = 0; r < 4; ++r) {
        int o = w * 64 + mi * 16 + ksel * 4 + r;
        int q = q0 + ni * 16 + lrow;
        ob[(size_t)o * 1600 + q] = (bf16)acc[mi][ni][r];
      }
    }
  }
}

// ---------------------------------------------------------------------------
// beta[b][hd][q] = sum_{c<64} bq[hd*64+c] * Kpm[b*1600+q][hd*64+c]   (bf16)
// ---------------------------------------------------------------------------
__global__ void beta_k(const bf16* __restrict__ Kpm, const float* __restrict__ bq,
                       bf16* __restrict__ beta) {
  __shared__ float bqs[256];
  const int t = threadIdx.x;
  bqs[t] = bq[t];
  __syncthreads();
  const int b = blockIdx.y;
  const int q = blockIdx.x * 64 + (t >> 2);
  const int hd = t & 3;
  const bf16* row = Kpm + ((size_t)b * 1600 + q) * 256 + hd * 64;
  float s = 0.f;
#pragma unroll
  for (int i = 0; i < 8; ++i) {
    bf16x8 v = *(const bf16x8*)(row + i * 8);
#pragma unroll
    for (int j = 0; j < 8; ++j) s += (float)v[j] * bqs[hd * 64 + i * 8 + j];
  }
  beta[((size_t)b * 4 + hd) * 1600 + q] = (bf16)s;
}

// ===========================================================================
// stream_score2: CHUNK-SPLIT partial score.
// Block (ptile, cid, b): handles i in [cid*64, cid*64+64) as 4 sub-chunks of
// 16, writes scorep[cid][b][hd][p] = 0.0625 * partial  (beta folded into cid 0).
// Grid 4x larger than R16 -> occupancy/overlap; everything else identical.
// ===========================================================================
__global__ __launch_bounds__(256, 3)
void stream_score2(const float* __restrict__ query, const bf16* __restrict__ T,
                   const bf16* __restrict__ beta, float* __restrict__ scorep) {
  __shared__ alignas(16) bf16 Tc[2][64][192];  // 49.2KB dbuf
  __shared__ bf16 Bs[4][192];
  const int t = threadIdx.x;
  const int ptile = blockIdx.x >> 2;
  const int cid = blockIdx.x & 3;
  const int p0 = ptile * 256;
  const int b = blockIdx.y;
  const int px = p0 + t;
  const int x = px / 80, y = px % 80;

  // block-uniform q-window base (proven in R16)
  const int x_min = p0 / 80;
  int ixm = (int)floorf(0.5f * x_min - 0.25f);
  int xr0 = ixm < 0 ? 0 : ixm;
  int qbase = xr0 * 40;
  if (qbase > 1408) qbase = 1408;

  // per-thread interp (registers)
  float cx = 0.5f * x - 0.25f;
  int ix = (int)floorf(cx);
  float wx1 = cx - ix;
  int x0 = ix < 0 ? 0 : ix, x1 = (ix + 1 > 39) ? 39 : ix + 1;
  float cy = 0.5f * y - 0.25f;
  int iy = (int)floorf(cy);
  float wy1 = cy - iy;
  int y0 = iy < 0 ? 0 : iy, y1 = (iy + 1 > 39) ? 39 : iy + 1;
  const float w00 = (1.f - wx1) * (1.f - wy1), w01 = (1.f - wx1) * wy1;
  const float w10 = wx1 * (1.f - wy1), w11 = wx1 * wy1;
  const int r00 = x0 * 40 + y0 - qbase, r01 = x0 * 40 + y1 - qbase;
  const int r10 = x1 * 40 + y0 - qbase, r11 = x1 * 40 + y1 - qbase;

  if (cid == 0) {
    for (int i = t; i < 768; i += 256) {
      int hd = i / 192, qq = i - hd * 192;
      Bs[hd][qq] = beta[((size_t)b * 4 + hd) * 1600 + qbase + qq];
    }
  }

  const bf16* Tb = T + (size_t)b * 4 * 256 * 1600;

  auto STAGE = [&](int c, int buf) {
    const int k0 = c * 16;
#pragma unroll
    for (int call = 0; call < 6; ++call) {
      int idx = call * 256 + t;        // 1536 units: row r = idx/24, u = idx%24
      int r = idx / 24, u = idx - r * 24;
      int hd = r >> 4, kk = r & 15;
      const bf16* src = Tb + ((size_t)(hd * 256) + k0 + kk) * 1600 + qbase + u * 8;
      gl16(src, &Tc[buf][0][0] + idx * 8);
    }
  };

  const int c0 = cid * 4;
  STAGE(c0, 0);
  asm volatile("s_waitcnt vmcnt(0)" ::: "memory");
  __syncthreads();

  float acc[4];
  if (cid == 0) {
#pragma unroll
    for (int hd = 0; hd < 4; ++hd)
      acc[hd] = w00 * (float)Bs[hd][r00] + w01 * (float)Bs[hd][r01] +
                w10 * (float)Bs[hd][r10] + w11 * (float)Bs[hd][r11];
  } else {
#pragma unroll
    for (int hd = 0; hd < 4; ++hd) acc[hd] = 0.f;
  }

  int buf = 0;
  for (int s = 0; s < 4; ++s) {
    if (s < 3) STAGE(c0 + s + 1, buf ^ 1);
    float qv[16];
#pragma unroll
    for (int kk = 0; kk < 16; ++kk)
      qv[kk] = query[((size_t)b * 256 + (c0 + s) * 16 + kk) * 6400 + px];
#pragma unroll
    for (int kk = 0; kk < 16; ++kk) {
#pragma unroll
      for (int hd = 0; hd < 4; ++hd) {
        const bf16* row = &Tc[buf][hd * 16 + kk][0];
        float tv = w00 * (float)row[r00] + w01 * (float)row[r01] +
                   w10 * (float)row[r10] + w11 * (float)row[r11];
        acc[hd] += qv[kk] * tv;
      }
    }
    asm volatile("s_waitcnt vmcnt(0)" ::: "memory");
    __syncthreads();
    buf ^= 1;
  }

#pragma unroll
  for (int hd = 0; hd < 4; ++hd)
    scorep[(((size_t)cid * 16 + b) * 4 + hd) * 6400 + px] = 0.0625f * acc[hd];
}

// ---------------------------------------------------------------------------
// smax: sum 4 partial planes, then in-place column softmax over x (x4 folded).
// ---------------------------------------------------------------------------
__global__ void smax_kernel(const float* __restrict__ scorep, float* __restrict__ score) {
  __shared__ float s[6400];
  const int hd = blockIdx.x, b = blockIdx.y, t = threadIdx.x;
  float* buf = score + ((size_t)b * 4 + hd) * 6400;
  for (int i = t; i < 6400; i += 256) {
    float v = 0.f;
#pragma unroll
    for (int c = 0; c < 4; ++c)
      v += scorep[(((size_t)c * 16 + b) * 4 + hd) * 6400 + i];
    s[i] = v;
  }
  __syncthreads();
  if (t < 80) {
    const int y = t;
    float m = -1e30f;
    for (int x = 0; x < 80; ++x) m = fmaxf(m, s[x * 80 + y]);
    float sum = 0.f;
    for (int x = 0; x < 80; ++x) {
      float e = __expf(s[x * 80 + y] - m);
      s[x * 80 + y] = e;
      sum += e;
    }
    float inv = 4.0f / sum;
    for (int x = 0; x < 80; ++x) buf[x * 80 + y] = s[x * 80 + y] * inv;
  }
}

// ===========================================================================
// combine (unchanged): one block per (o, b), coalesced writes.
// ===========================================================================
__global__ __launch_bounds__(256, 8)
void combine(const bf16* __restrict__ Uv, const float* __restrict__ attn,
             const float* __restrict__ bo, float* __restrict__ out) {
  __shared__ bf16 Us[4][1600];
  __shared__ int   sx0[80], sx1[80];
  __shared__ float swx[80];
  const int t = threadIdx.x;
  const int o = blockIdx.x;
  const int b = blockIdx.y;

  const bf16* usrc = Uv + (size_t)(b * 4) * 256 * 1600 + (size_t)o * 1600;
  for (int idx = t; idx < 800; idx += 256) {
    int hd = idx / 200, u = idx % 200;
    *(bf16x8*)&Us[hd][u * 8] = *(const bf16x8*)(usrc + (size_t)hd * 256 * 1600 + u * 8);
  }
  if (t < 80) {
    float c = 0.5f * t - 0.25f;
    int i0 = (int)floorf(c);
    swx[t] = c - i0;
    sx0[t] = i0 < 0 ? 0 : i0;
    sx1[t] = (i0 + 1 > 39) ? 39 : i0 + 1;
  }
  __syncthreads();

  const float bias = bo[o];
  const float* attb = attn + (size_t)b * 4 * 6400;
  float* op = out + ((size_t)b * 256 + o) * 6400;

  for (int p = t; p < 6400; p += 256) {
    int x = p / 80, y = p - x * 80;
    int x0 = sx0[x], x1 = sx1[x], y0 = sx0[y], y1 = sx1[y];
    float wx1 = swx[x], wy1 = swx[y];
    float w00 = (1.f - wx1) * (1.f - wy1), w01 = (1.f - wx1) * wy1;
    float w10 = wx1 * (1.f - wy1), w11 = wx1 * wy1;
    int q00 = x0 * 40 + y0, q01 = x0 * 40 + y1, q10 = x1 * 40 + y0, q11 = x1 * 40 + y1;
    float acc = bias;
#pragma unroll
    for (int hd = 0; hd < 4; ++hd) {
      float up = w00 * (float)Us[hd][q00] + w01 * (float)Us[hd][q01] +
                 w10 * (float)Us[hd][q10] + w11 * (float)Us[hd][q11];
      acc += attb[hd * 6400 + p] * up;
    }
    op[p] = acc;
  }
}

// ---------------------------------------------------------------------------
extern "C" void kernel_launch(void* const* d_in, const int* in_sizes, int n_in,
                              void* d_out, int out_size, void* d_ws, size_t ws_size,
                              hipStream_t stream) {
  const float* query = (const float*)d_in[0];
  const float* key   = (const float*)d_in[1];
  const float* wq    = (const float*)d_in[2];
  const float* bq    = (const float*)d_in[3];
  const float* wk    = (const float*)d_in[4];
  const float* bk    = (const float*)d_in[5];
  const float* wv    = (const float*)d_in[6];
  const float* bv    = (const float*)d_in[7];
  const float* wo    = (const float*)d_in[8];
  const float* bo    = (const float*)d_in[9];

  // ws (85.7MB): [T | later Uv] | Kpm | Vpm | score | Wb.
  // d_out scratch (dead before combine): wqT | beta | scorep (26.2MB).
  char* ws = (char*)d_ws;
  bf16*  T     = (bf16*)(ws);              // 52,428,800 B (dead after stream_score2)
  bf16*  Uv    = (bf16*)(ws);              // written by uv_gemm (after smax)
  bf16*  Kpm   = (bf16*)(ws + 52428800);   // 13,107,200 B
  bf16*  Vpm   = (bf16*)(ws + 65536000);   // 13,107,200 B
  float* score = (float*)(ws + 78643200);  //  6,553,600 B
  bf16*  Wb    = (bf16*)(ws + 85196800);   //    524,288 B
  bf16* wkb = Wb + 65536, *wvb = Wb + 131072, *wob = Wb + 196608;
  bf16*  wqT    = (bf16*)d_out;                      //   131,072 B scratch
  bf16*  beta   = (bf16*)((char*)d_out + 131072);    //   204,800 B scratch
  float* scorep = (float*)((char*)d_out + 1048576);  // 26,214,400 B scratch

  wpre<<<dim3(32, 4), 256, 0, stream>>>(wq, wk, wv, wo, Wb);
  wtr<<<dim3(4, 4), 256, 0, stream>>>(wq, wqT);
  kv_proj<<<dim3(25, 2, 16), 256, 0, stream>>>(key, wkb, bk, Kpm, wvb, bv, Vpm);
  uv_gemm<<<dim3(25, 4, 16), 256, 0, stream>>>(Kpm, wqT, T);    // T-gemm
  beta_k<<<dim3(25, 16), 256, 0, stream>>>(Kpm, bq, beta);
  stream_score2<<<dim3(100, 16), 256, 0, stream>>>(query, T, beta, scorep);
  smax_kernel<<<dim3(4, 16), 256, 0, stream>>>(scorep, score);
  uv_gemm<<<dim3(25, 4, 16), 256, 0, stream>>>(Vpm, wob, Uv);
  combine<<<dim3(256, 16), 256, 0, stream>>>(Uv, score, bo, (float*)d_out);
}